// Round 4
// baseline (313.941 us; speedup 1.0000x reference)
//
#include <hip/hip_runtime.h>
#include <math.h>

#define N_NODES 20000
#define N_EDGES 320000
#define ETOT (N_EDGES + N_NODES)
#define HID 16
#define OMEGA 100.0f
#define BETA 0.2f

__device__ __forceinline__ float sinrev(float x) { return __builtin_amdgcn_sinf(x); }
__device__ __forceinline__ float fract_f(float x) { return __builtin_amdgcn_fractf(x); }

__device__ __forceinline__ float selu_f(float v) {
    const float a  = 1.6732632423543772f;
    const float sc = 1.0507009873554805f;
    return sc * (v > 0.f ? v : a * expm1f(v));
}

// ---------------------------------------------------------------- weight prescale
// dst layout (624 floats): [0:64) s*w0, [64:80) s*b0, [80:336) s*w1,
// [336:352) s*b1, [352:608) s*w2, [608:624) s*b2   with s = OMEGA/(2*pi)
__global__ __launch_bounds__(256) void prep_kernel(
    const float* __restrict__ w0, const float* __restrict__ b0,
    const float* __restrict__ w1, const float* __restrict__ b1,
    const float* __restrict__ w2, const float* __restrict__ b2,
    float* __restrict__ dst)
{
    int i = blockIdx.x * 256 + threadIdx.x;
    const float s = OMEGA * 0.15915494309189535f;  // omega / (2*pi)
    if (i < 64)       dst[i] = s * w0[i];
    else if (i < 80)  dst[i] = s * b0[i - 64];
    else if (i < 336) dst[i] = s * w1[i - 80];
    else if (i < 352) dst[i] = s * b1[i - 336];
    else if (i < 608) dst[i] = s * w2[i - 352];
    else if (i < 624) dst[i] = s * b2[i - 608];
}

// ---------------------------------------------------------------- self-loop MLP chain
// feat == 0 for self loops: h-chain depends only on channel o. h2v[o][g].
template<int OUT>
__global__ void hfin_kernel(const float* __restrict__ SW, float* __restrict__ h2v)
{
    int o = threadIdx.x;
    if (o >= OUT) return;
    const float* sw0 = SW;
    const float* sb0 = SW + 64;
    const float* sw1 = SW + 80;
    const float* sb1 = SW + 336;
    const float* sw2 = SW + 352;
    const float* sb2 = SW + 608;
    float oc = (float)o;
    float h0[HID], h1[HID];
#pragma unroll
    for (int h = 0; h < HID; h++)
        h0[h] = sinrev(fract_f(fmaf(oc, sw0[h * 4 + 3], sb0[h])));
#pragma unroll
    for (int g = 0; g < HID; g++) {
        float sa = sb1[g];
#pragma unroll
        for (int h = 0; h < HID; h++) sa += h0[h] * sw1[g * HID + h];
        h1[g] = sinrev(sa);
    }
#pragma unroll
    for (int g = 0; g < HID; g++) {
        float sa = sb2[g];
#pragma unroll
        for (int h = 0; h < HID; h++) sa += h1[h] * sw2[g * HID + h];
        h2v[o * HID + g] = sinrev(sa);
    }
}

// ---------------------------------------------------------------- edge feats
__global__ __launch_bounds__(256) void edge_feat_kernel(
    const int* __restrict__ ei, const float* __restrict__ pos,
    float4* __restrict__ feat)
{
    int e = blockIdx.x * 256 + threadIdx.x;
    if (e >= N_EDGES) return;
    int s = ei[e], d = ei[N_EDGES + e];
    float rx = pos[d * 3 + 0] - pos[s * 3 + 0];
    float ry = pos[d * 3 + 1] - pos[s * 3 + 1];
    float rz = pos[d * 3 + 2] - pos[s * 3 + 2];
    float sq = rx * rx + ry * ry + rz * rz;
    float4 f = make_float4(0.f, 0.f, 0.f, 0.f);
    if (sq > 0.f) {
        float rho = sqrtf(sq);
        float th  = atan2f(ry, rx);
        float ph  = asinf(fminf(fmaxf(rz / rho, -1.f), 1.f));
        const float inv_pi = 0.31830988618379067f;
        f = make_float4(rho, th * inv_pi, ph * inv_pi, 0.f);
    }
    feat[e] = f;
}

// ---------------------------------------------------------------- x -> xcat
__global__ __launch_bounds__(256) void copy_x_kernel(
    const float* __restrict__ x, float* __restrict__ xcat)
{
    int i = blockIdx.x * 256 + threadIdx.x;
    if (i >= N_NODES * 16) return;
    int n = i >> 4, c = i & 15;
    xcat[n * 32 + c] = x[i];
}

// ---------------------------------------------------------------- per-edge t
// t[e][h] = sum_i xcat[src(e)][i] * wl[i][h];  blx[e] = sum_i xcat[src(e)][i]*bl[i]
template<int IN>
__global__ __launch_bounds__(256) void tbuf_kernel(
    const int* __restrict__ ei, const float* __restrict__ xcat,
    const float* __restrict__ wl, const float* __restrict__ bl,
    float4* __restrict__ tbuf, float* __restrict__ blxb)
{
    int e = blockIdx.x * 256 + threadIdx.x;
    if (e >= ETOT) return;
    int s = (e < N_EDGES) ? ei[e] : e - N_EDGES;

    float t[HID];
#pragma unroll
    for (int h = 0; h < HID; h++) t[h] = 0.f;
    float blx = 0.f;
    const float4* xr = (const float4*)(xcat + s * 32);
#pragma unroll
    for (int i4 = 0; i4 < IN / 4; i4++) {
        float4 xv = xr[i4];
        blx += bl[i4 * 4 + 0] * xv.x + bl[i4 * 4 + 1] * xv.y
             + bl[i4 * 4 + 2] * xv.z + bl[i4 * 4 + 3] * xv.w;
#pragma unroll
        for (int h = 0; h < HID; h++) {
            t[h] += wl[(i4 * 4 + 0) * HID + h] * xv.x
                  + wl[(i4 * 4 + 1) * HID + h] * xv.y
                  + wl[(i4 * 4 + 2) * HID + h] * xv.z
                  + wl[(i4 * 4 + 3) * HID + h] * xv.w;
        }
    }
#pragma unroll
    for (int q = 0; q < 4; q++)
        tbuf[(size_t)e * 4 + q] = make_float4(t[q*4+0], t[q*4+1], t[q*4+2], t[q*4+3]);
    blxb[e] = blx;
}

// ---------------------------------------------------------------- conv edge-channel
// one thread per (real edge, out-channel); self loops handled in finishers
template<int OUT, int LOG2OUT>
__global__ __launch_bounds__(256, 4) void conv_eo_kernel(
    const int* __restrict__ ei, const float4* __restrict__ feat,
    const float* __restrict__ SW,
    const float4* __restrict__ tbuf, const float* __restrict__ blxb,
    float* __restrict__ acc)
{
    const float* sw0 = SW;          // [h*4 + k]
    const float* sb0 = SW + 64;
    const float* sw1 = SW + 80;     // [g*16 + h]
    const float* sb1 = SW + 336;
    const float* sw2 = SW + 352;    // [g*16 + h]
    const float* sb2 = SW + 608;

    int i = blockIdx.x * 256 + threadIdx.x;
    if (i >= N_EDGES * OUT) return;
    int e = i >> LOG2OUT;
    int o = i & (OUT - 1);
    int d = ei[N_EDGES + e];

    float4 f = feat[e];
    float oc = (float)o;

    // layer 1 (phases up to ~100 revolutions -> fract range reduction)
    float h0[HID];
#pragma unroll
    for (int h = 0; h < HID; h++) {
        float ph = sb0[h] + f.x * sw0[h * 4 + 0] + f.y * sw0[h * 4 + 1]
                 + f.z * sw0[h * 4 + 2] + oc * sw0[h * 4 + 3];
        h0[h] = sinrev(fract_f(ph));
    }
    // layer 2
    float h1[HID];
#pragma unroll
    for (int g = 0; g < HID; g++) {
        float sa = sb1[g];
#pragma unroll
        for (int h = 0; h < HID; h++) sa += h0[h] * sw1[g * HID + h];
        h1[g] = sinrev(sa);
    }
    // layer 3 + dot with t (t loaded lazily, 4 at a time)
    float m = blxb[e];
#pragma unroll
    for (int q = 0; q < 4; q++) {
        float4 tv = tbuf[(size_t)e * 4 + q];
        float tvv[4] = {tv.x, tv.y, tv.z, tv.w};
#pragma unroll
        for (int j = 0; j < 4; j++) {
            int g = q * 4 + j;
            float sa = sb2[g];
#pragma unroll
            for (int h = 0; h < HID; h++) sa += h1[h] * sw2[g * HID + h];
            m += sinrev(sa) * tvv[j];
        }
    }
    atomicAdd(&acc[d * OUT + o], m);
}

// ---------------------------------------------------------------- finishers (+ self-loop term)
template<int OUT>
__global__ __launch_bounds__(256) void finish_mid_kernel(
    const float* __restrict__ acc, const float* __restrict__ bias,
    const float* __restrict__ h2v,
    const float4* __restrict__ tbuf, const float* __restrict__ blxb,
    float* __restrict__ xcat, int coloff)
{
    int i = blockIdx.x * 256 + threadIdx.x;
    if (i >= N_NODES * OUT) return;
    int n = i / OUT, o = i % OUT;
    const float* tr = (const float*)&tbuf[(size_t)(N_EDGES + n) * 4];
    float m = blxb[N_EDGES + n];
#pragma unroll
    for (int h = 0; h < HID; h++) m += h2v[o * HID + h] * tr[h];
    xcat[n * 32 + coloff + o] = selu_f(acc[i] + bias[o] + m);
}

__global__ __launch_bounds__(256) void finish_out_kernel(
    const float* __restrict__ acc, const float* __restrict__ bias,
    const float* __restrict__ h2v,
    const float4* __restrict__ tbuf, const float* __restrict__ blxb,
    const float* __restrict__ x, float* __restrict__ out)
{
    int i = blockIdx.x * 256 + threadIdx.x;
    if (i >= N_NODES * 16) return;
    int n = i >> 4, c = i & 15;
    const float* tr = (const float*)&tbuf[(size_t)(N_EDGES + n) * 4];
    float m = blxb[N_EDGES + n];
#pragma unroll
    for (int h = 0; h < HID; h++) m += h2v[c * HID + h] * tr[h];
    out[i] = x[i] + BETA * selu_f(acc[i] + bias[c] + m);
}

// ---------------------------------------------------------------- launch
extern "C" void kernel_launch(void* const* d_in, const int* in_sizes, int n_in,
                              void* d_out, int out_size, void* d_ws, size_t ws_size,
                              hipStream_t stream)
{
    const float* x   = (const float*)d_in[0];
    const int*   ei  = (const int*)d_in[1];
    const float* pos = (const float*)d_in[2];

    const float* W[27];
    for (int i = 0; i < 27; i++) W[i] = (const float*)d_in[3 + i];
    // per conv c (0-based): w0=W[9c+0] b0=+1 w1=+2 b1=+3 w2=+4 b2=+5 wl=+6 bl=+7 bias=+8

    float* ws    = (float*)d_ws;
    float4* feat = (float4*)ws;                    // N_EDGES*4 floats
    float* xcat  = ws + (size_t)ETOT * 4;          // N*32
    float* acc1  = xcat + (size_t)N_NODES * 32;    // N*8
    float* acc2  = acc1 + (size_t)N_NODES * 8;     // N*8
    float* acc3  = acc2 + (size_t)N_NODES * 8;     // N*16
    float* sw1   = acc3 + (size_t)N_NODES * 16;    // 624
    float* sw2   = sw1 + 624;                      // 624
    float* sw3   = sw2 + 624;                      // 624
    float* h2v1  = sw3 + 624;                      // 128
    float* h2v2  = h2v1 + 256;                     // 128
    float* h2v3  = h2v2 + 256;                     // 256
    float4* tbuf = (float4*)(h2v3 + 256);          // ETOT*16 floats
    float* blxb  = (float*)(tbuf + (size_t)ETOT * 4); // ETOT
    float* out   = (float*)d_out;

    hipMemsetAsync(acc1, 0, (size_t)N_NODES * 32 * sizeof(float), stream);

    dim3 blk(256);
    dim3 gef((N_EDGES + 255) / 256);
    dim3 ge((ETOT + 255) / 256);
    dim3 gx((N_NODES * 16 + 255) / 256);
    dim3 g8((N_NODES * 8 + 255) / 256);
    dim3 geo8(((size_t)N_EDGES * 8 + 255) / 256);
    dim3 geo16(((size_t)N_EDGES * 16 + 255) / 256);

    prep_kernel<<<3, blk, 0, stream>>>(W[0],  W[1],  W[2],  W[3],  W[4],  W[5],  sw1);
    prep_kernel<<<3, blk, 0, stream>>>(W[9],  W[10], W[11], W[12], W[13], W[14], sw2);
    prep_kernel<<<3, blk, 0, stream>>>(W[18], W[19], W[20], W[21], W[22], W[23], sw3);
    hfin_kernel<8><<<1, 64, 0, stream>>>(sw1, h2v1);
    hfin_kernel<8><<<1, 64, 0, stream>>>(sw2, h2v2);
    hfin_kernel<16><<<1, 64, 0, stream>>>(sw3, h2v3);

    edge_feat_kernel<<<gef, blk, 0, stream>>>(ei, pos, feat);
    copy_x_kernel<<<gx, blk, 0, stream>>>(x, xcat);

    tbuf_kernel<16><<<ge, blk, 0, stream>>>(ei, xcat, W[6], W[7], tbuf, blxb);
    conv_eo_kernel<8, 3><<<geo8, blk, 0, stream>>>(ei, feat, sw1, tbuf, blxb, acc1);
    finish_mid_kernel<8><<<g8, blk, 0, stream>>>(acc1, W[8], h2v1, tbuf, blxb, xcat, 16);

    tbuf_kernel<24><<<ge, blk, 0, stream>>>(ei, xcat, W[15], W[16], tbuf, blxb);
    conv_eo_kernel<8, 3><<<geo8, blk, 0, stream>>>(ei, feat, sw2, tbuf, blxb, acc2);
    finish_mid_kernel<8><<<g8, blk, 0, stream>>>(acc2, W[17], h2v2, tbuf, blxb, xcat, 24);

    tbuf_kernel<32><<<ge, blk, 0, stream>>>(ei, xcat, W[24], W[25], tbuf, blxb);
    conv_eo_kernel<16, 4><<<geo16, blk, 0, stream>>>(ei, feat, sw3, tbuf, blxb, acc3);
    finish_out_kernel<<<gx, blk, 0, stream>>>(acc3, W[26], h2v3, tbuf, blxb, x, out);
}

// Round 5
// 275.579 us; speedup vs baseline: 1.1392x; 1.1392x over previous
//
#include <hip/hip_runtime.h>
#include <math.h>

#define N_NODES 20000
#define N_EDGES 320000
#define ETOT (N_EDGES + N_NODES)
#define HID 16
#define OMEGA 100.0f
#define BETA 0.2f

typedef float v2f __attribute__((ext_vector_type(2)));

__device__ __forceinline__ float sinrev(float x) { return __builtin_amdgcn_sinf(x); }
__device__ __forceinline__ float fract_f(float x) { return __builtin_amdgcn_fractf(x); }
__device__ __forceinline__ v2f fma2(v2f a, v2f b, v2f c) { return __builtin_elementwise_fma(a, b, c); }

__device__ __forceinline__ float selu_f(float v) {
    const float a  = 1.6732632423543772f;
    const float sc = 1.0507009873554805f;
    return sc * (v > 0.f ? v : a * expm1f(v));
}

// ---------------------------------------------------------------- weight prescale
// dst layout (624 floats), s = OMEGA/(2*pi):
// [0:16) s*w0 x-col, [16:32) y-col, [32:48) z-col, [48:64) chan-col  (col-major!)
// [64:80) s*b0, [80:336) s*w1 [g*16+h], [336:352) s*b1,
// [352:608) s*w2 [g*16+h], [608:624) s*b2
__global__ __launch_bounds__(256) void prep_kernel(
    const float* __restrict__ w0, const float* __restrict__ b0,
    const float* __restrict__ w1, const float* __restrict__ b1,
    const float* __restrict__ w2, const float* __restrict__ b2,
    float* __restrict__ dst)
{
    int i = blockIdx.x * 256 + threadIdx.x;
    const float s = OMEGA * 0.15915494309189535f;  // omega / (2*pi)
    if (i < 64) {
        int h = i >> 2, k = i & 3;          // w0 is [h][4]
        dst[k * 16 + h] = s * w0[i];
    }
    else if (i < 80)  dst[i] = s * b0[i - 64];
    else if (i < 336) dst[i] = s * w1[i - 80];
    else if (i < 352) dst[i] = s * b1[i - 336];
    else if (i < 608) dst[i] = s * w2[i - 352];
    else if (i < 624) dst[i] = s * b2[i - 608];
}

// ---------------------------------------------------------------- self-loop MLP chain
// feat == 0 for self loops: h-chain depends only on channel o. h2v[o][g].
template<int OUT>
__global__ void hfin_kernel(const float* __restrict__ SW, float* __restrict__ h2v)
{
    int o = threadIdx.x;
    if (o >= OUT) return;
    const float* w0c = SW + 48;
    const float* sb0 = SW + 64;
    const float* sw1 = SW + 80;
    const float* sb1 = SW + 336;
    const float* sw2 = SW + 352;
    const float* sb2 = SW + 608;
    float oc = (float)o;
    float h0[HID], h1[HID];
#pragma unroll
    for (int h = 0; h < HID; h++)
        h0[h] = sinrev(fract_f(fmaf(oc, w0c[h], sb0[h])));
#pragma unroll
    for (int g = 0; g < HID; g++) {
        float sa = sb1[g];
#pragma unroll
        for (int h = 0; h < HID; h++) sa += h0[h] * sw1[g * HID + h];
        h1[g] = sinrev(sa);
    }
#pragma unroll
    for (int g = 0; g < HID; g++) {
        float sa = sb2[g];
#pragma unroll
        for (int h = 0; h < HID; h++) sa += h1[h] * sw2[g * HID + h];
        h2v[o * HID + g] = sinrev(sa);
    }
}

// ---------------------------------------------------------------- edge feats
__global__ __launch_bounds__(256) void edge_feat_kernel(
    const int* __restrict__ ei, const float* __restrict__ pos,
    float4* __restrict__ feat)
{
    int e = blockIdx.x * 256 + threadIdx.x;
    if (e >= N_EDGES) return;
    int s = ei[e], d = ei[N_EDGES + e];
    float rx = pos[d * 3 + 0] - pos[s * 3 + 0];
    float ry = pos[d * 3 + 1] - pos[s * 3 + 1];
    float rz = pos[d * 3 + 2] - pos[s * 3 + 2];
    float sq = rx * rx + ry * ry + rz * rz;
    float4 f = make_float4(0.f, 0.f, 0.f, 0.f);
    if (sq > 0.f) {
        float rho = sqrtf(sq);
        float th  = atan2f(ry, rx);
        float ph  = asinf(fminf(fmaxf(rz / rho, -1.f), 1.f));
        const float inv_pi = 0.31830988618379067f;
        f = make_float4(rho, th * inv_pi, ph * inv_pi, 0.f);
    }
    feat[e] = f;
}

// ---------------------------------------------------------------- x -> xcat
__global__ __launch_bounds__(256) void copy_x_kernel(
    const float* __restrict__ x, float* __restrict__ xcat)
{
    int i = blockIdx.x * 256 + threadIdx.x;
    if (i >= N_NODES * 16) return;
    int n = i >> 4, c = i & 15;
    xcat[n * 32 + c] = x[i];
}

// ---------------------------------------------------------------- per-edge t
template<int IN>
__global__ __launch_bounds__(256) void tbuf_kernel(
    const int* __restrict__ ei, const float* __restrict__ xcat,
    const float* __restrict__ wl, const float* __restrict__ bl,
    float4* __restrict__ tbuf, float* __restrict__ blxb)
{
    int e = blockIdx.x * 256 + threadIdx.x;
    if (e >= ETOT) return;
    int s = (e < N_EDGES) ? ei[e] : e - N_EDGES;

    float t[HID];
#pragma unroll
    for (int h = 0; h < HID; h++) t[h] = 0.f;
    float blx = 0.f;
    const float4* xr = (const float4*)(xcat + s * 32);
#pragma unroll
    for (int i4 = 0; i4 < IN / 4; i4++) {
        float4 xv = xr[i4];
        blx += bl[i4 * 4 + 0] * xv.x + bl[i4 * 4 + 1] * xv.y
             + bl[i4 * 4 + 2] * xv.z + bl[i4 * 4 + 3] * xv.w;
#pragma unroll
        for (int h = 0; h < HID; h++) {
            t[h] += wl[(i4 * 4 + 0) * HID + h] * xv.x
                  + wl[(i4 * 4 + 1) * HID + h] * xv.y
                  + wl[(i4 * 4 + 2) * HID + h] * xv.z
                  + wl[(i4 * 4 + 3) * HID + h] * xv.w;
        }
    }
#pragma unroll
    for (int q = 0; q < 4; q++)
        tbuf[(size_t)e * 4 + q] = make_float4(t[q*4+0], t[q*4+1], t[q*4+2], t[q*4+3]);
    blxb[e] = blx;
}

// ---------------------------------------------------------------- conv edge-channel
// one thread per (real edge, out-channel); packed 2xfp32 math throughout
template<int OUT, int LOG2OUT>
__global__ __launch_bounds__(256, 4) void conv_eo_kernel(
    const int* __restrict__ ei, const float4* __restrict__ feat,
    const float* __restrict__ SW,
    const float4* __restrict__ tbuf, const float* __restrict__ blxb,
    float* __restrict__ acc)
{
    const v2f* wx   = (const v2f*)(SW);        // 8 h-pairs per column
    const v2f* wy   = (const v2f*)(SW + 16);
    const v2f* wz   = (const v2f*)(SW + 32);
    const v2f* wc   = (const v2f*)(SW + 48);
    const v2f* b0p  = (const v2f*)(SW + 64);
    const float* sw1 = SW + 80;                // [g*16+h]
    const float* sb1 = SW + 336;
    const float* sw2 = SW + 352;               // [g*16+h]
    const float* sb2 = SW + 608;

    int i = blockIdx.x * 256 + threadIdx.x;
    if (i >= N_EDGES * OUT) return;
    int e = i >> LOG2OUT;
    int o = i & (OUT - 1);
    int d = ei[N_EDGES + e];

    float4 f = feat[e];
    v2f fx = {f.x, f.x}, fy = {f.y, f.y}, fz = {f.z, f.z};
    float ocs = (float)o;
    v2f oc = {ocs, ocs};

    // layer 1 (phases up to ~100 revolutions -> fract range reduction)
    v2f h0p[8];
#pragma unroll
    for (int hh = 0; hh < 8; hh++) {
        v2f ph = fma2(fx, wx[hh], b0p[hh]);
        ph = fma2(fy, wy[hh], ph);
        ph = fma2(fz, wz[hh], ph);
        ph = fma2(oc, wc[hh], ph);
        h0p[hh] = (v2f){ sinrev(fract_f(ph.x)), sinrev(fract_f(ph.y)) };
    }

    // layer 2: pairs of g rows, each row = dot of 8 h-pairs
    v2f h1p[8];
#pragma unroll
    for (int gp = 0; gp < 8; gp++) {
        const v2f* wa = (const v2f*)(sw1 + (2 * gp) * HID);
        const v2f* wb = (const v2f*)(sw1 + (2 * gp + 1) * HID);
        v2f aa = h0p[0] * wa[0];
        v2f bb = h0p[0] * wb[0];
#pragma unroll
        for (int hh = 1; hh < 8; hh++) {
            aa = fma2(h0p[hh], wa[hh], aa);
            bb = fma2(h0p[hh], wb[hh], bb);
        }
        float sa = aa.x + aa.y + sb1[2 * gp];
        float sb = bb.x + bb.y + sb1[2 * gp + 1];
        h1p[gp] = (v2f){ sinrev(sa), sinrev(sb) };
    }

    // layer 3 + packed dot with t
    const v2f* tp = (const v2f*)(tbuf + (size_t)e * 4);
    v2f mm = { blxb[e], 0.f };
#pragma unroll
    for (int gp = 0; gp < 8; gp++) {
        const v2f* wa = (const v2f*)(sw2 + (2 * gp) * HID);
        const v2f* wb = (const v2f*)(sw2 + (2 * gp + 1) * HID);
        v2f aa = h1p[0] * wa[0];
        v2f bb = h1p[0] * wb[0];
#pragma unroll
        for (int hh = 1; hh < 8; hh++) {
            aa = fma2(h1p[hh], wa[hh], aa);
            bb = fma2(h1p[hh], wb[hh], bb);
        }
        float sa = aa.x + aa.y + sb2[2 * gp];
        float sb = bb.x + bb.y + sb2[2 * gp + 1];
        v2f s2 = { sinrev(sa), sinrev(sb) };
        mm = fma2(s2, tp[gp], mm);
    }
    float m = mm.x + mm.y;

    atomicAdd(&acc[d * OUT + o], m);
}

// ---------------------------------------------------------------- finishers (+ self-loop term)
template<int OUT>
__global__ __launch_bounds__(256) void finish_mid_kernel(
    const float* __restrict__ acc, const float* __restrict__ bias,
    const float* __restrict__ h2v,
    const float4* __restrict__ tbuf, const float* __restrict__ blxb,
    float* __restrict__ xcat, int coloff)
{
    int i = blockIdx.x * 256 + threadIdx.x;
    if (i >= N_NODES * OUT) return;
    int n = i / OUT, o = i % OUT;
    const float* tr = (const float*)&tbuf[(size_t)(N_EDGES + n) * 4];
    float m = blxb[N_EDGES + n];
#pragma unroll
    for (int h = 0; h < HID; h++) m += h2v[o * HID + h] * tr[h];
    xcat[n * 32 + coloff + o] = selu_f(acc[i] + bias[o] + m);
}

__global__ __launch_bounds__(256) void finish_out_kernel(
    const float* __restrict__ acc, const float* __restrict__ bias,
    const float* __restrict__ h2v,
    const float4* __restrict__ tbuf, const float* __restrict__ blxb,
    const float* __restrict__ x, float* __restrict__ out)
{
    int i = blockIdx.x * 256 + threadIdx.x;
    if (i >= N_NODES * 16) return;
    int n = i >> 4, c = i & 15;
    const float* tr = (const float*)&tbuf[(size_t)(N_EDGES + n) * 4];
    float m = blxb[N_EDGES + n];
#pragma unroll
    for (int h = 0; h < HID; h++) m += h2v[c * HID + h] * tr[h];
    out[i] = x[i] + BETA * selu_f(acc[i] + bias[c] + m);
}

// ---------------------------------------------------------------- launch
extern "C" void kernel_launch(void* const* d_in, const int* in_sizes, int n_in,
                              void* d_out, int out_size, void* d_ws, size_t ws_size,
                              hipStream_t stream)
{
    const float* x   = (const float*)d_in[0];
    const int*   ei  = (const int*)d_in[1];
    const float* pos = (const float*)d_in[2];

    const float* W[27];
    for (int i = 0; i < 27; i++) W[i] = (const float*)d_in[3 + i];
    // per conv c (0-based): w0=W[9c+0] b0=+1 w1=+2 b1=+3 w2=+4 b2=+5 wl=+6 bl=+7 bias=+8

    float* ws    = (float*)d_ws;
    float4* feat = (float4*)ws;                    // N_EDGES*4 floats
    float* xcat  = ws + (size_t)ETOT * 4;          // N*32
    float* acc1  = xcat + (size_t)N_NODES * 32;    // N*8
    float* acc2  = acc1 + (size_t)N_NODES * 8;     // N*8
    float* acc3  = acc2 + (size_t)N_NODES * 8;     // N*16
    float* sw1   = acc3 + (size_t)N_NODES * 16;    // 624
    float* sw2   = sw1 + 624;                      // 624
    float* sw3   = sw2 + 624;                      // 624
    float* h2v1  = sw3 + 624;                      // 128 (pad 256)
    float* h2v2  = h2v1 + 256;                     // 128 (pad 256)
    float* h2v3  = h2v2 + 256;                     // 256
    float4* tbuf = (float4*)(h2v3 + 256);          // ETOT*16 floats
    float* blxb  = (float*)(tbuf + (size_t)ETOT * 4); // ETOT
    float* out   = (float*)d_out;

    hipMemsetAsync(acc1, 0, (size_t)N_NODES * 32 * sizeof(float), stream);

    dim3 blk(256);
    dim3 gef((N_EDGES + 255) / 256);
    dim3 ge((ETOT + 255) / 256);
    dim3 gx((N_NODES * 16 + 255) / 256);
    dim3 g8((N_NODES * 8 + 255) / 256);
    dim3 geo8(((size_t)N_EDGES * 8 + 255) / 256);
    dim3 geo16(((size_t)N_EDGES * 16 + 255) / 256);

    prep_kernel<<<3, blk, 0, stream>>>(W[0],  W[1],  W[2],  W[3],  W[4],  W[5],  sw1);
    prep_kernel<<<3, blk, 0, stream>>>(W[9],  W[10], W[11], W[12], W[13], W[14], sw2);
    prep_kernel<<<3, blk, 0, stream>>>(W[18], W[19], W[20], W[21], W[22], W[23], sw3);
    hfin_kernel<8><<<1, 64, 0, stream>>>(sw1, h2v1);
    hfin_kernel<8><<<1, 64, 0, stream>>>(sw2, h2v2);
    hfin_kernel<16><<<1, 64, 0, stream>>>(sw3, h2v3);

    edge_feat_kernel<<<gef, blk, 0, stream>>>(ei, pos, feat);
    copy_x_kernel<<<gx, blk, 0, stream>>>(x, xcat);

    tbuf_kernel<16><<<ge, blk, 0, stream>>>(ei, xcat, W[6], W[7], tbuf, blxb);
    conv_eo_kernel<8, 3><<<geo8, blk, 0, stream>>>(ei, feat, sw1, tbuf, blxb, acc1);
    finish_mid_kernel<8><<<g8, blk, 0, stream>>>(acc1, W[8], h2v1, tbuf, blxb, xcat, 16);

    tbuf_kernel<24><<<ge, blk, 0, stream>>>(ei, xcat, W[15], W[16], tbuf, blxb);
    conv_eo_kernel<8, 3><<<geo8, blk, 0, stream>>>(ei, feat, sw2, tbuf, blxb, acc2);
    finish_mid_kernel<8><<<g8, blk, 0, stream>>>(acc2, W[17], h2v2, tbuf, blxb, xcat, 24);

    tbuf_kernel<32><<<ge, blk, 0, stream>>>(ei, xcat, W[24], W[25], tbuf, blxb);
    conv_eo_kernel<16, 4><<<geo16, blk, 0, stream>>>(ei, feat, sw3, tbuf, blxb, acc3);
    finish_out_kernel<<<gx, blk, 0, stream>>>(acc3, W[26], h2v3, tbuf, blxb, x, out);
}